// Round 13
// baseline (177.632 us; speedup 1.0000x reference)
//
#include <hip/hip_runtime.h>

#define E_DIM 512
#define N_DIM 512
#define B_DIM 32
#define H_DIM 8
#define D_DIM 8
#define P3    192   // 3 * H * D

typedef _Float16 half_t;
typedef __attribute__((ext_vector_type(2))) _Float16 half2v;
typedef __attribute__((ext_vector_type(4))) _Float16 half4v;
typedef __attribute__((ext_vector_type(8))) _Float16 half8v;
typedef __attribute__((ext_vector_type(4))) float f32x4;

#define PB_STRIDE 36   // hopfield P-scratch stride
#define XS_STRIDE 520  // ln x-tile stride (halves)

// ---------------------------------------------------------------------------
__device__ inline float block_reduce_256(float v) {
    __shared__ float red[4];
    #pragma unroll
    for (int m = 32; m >= 1; m >>= 1) v += __shfl_xor(v, m);
    int w = threadIdx.x >> 6;
    if ((threadIdx.x & 63) == 0) red[w] = v;
    __syncthreads();
    if (threadIdx.x == 0) v = red[0] + red[1] + red[2] + red[3];
    return v;
}

__device__ inline half8v cvt8(float4 a, float4 b) {
    half8v h;
    h[0] = (half_t)a.x; h[1] = (half_t)a.y; h[2] = (half_t)a.z; h[3] = (half_t)a.w;
    h[4] = (half_t)b.x; h[5] = (half_t)b.y; h[6] = (half_t)b.z; h[7] = (half_t)b.w;
    return h;
}

__device__ inline half2v pk2(float a, float b) {
    return __builtin_bit_cast(half2v, __builtin_amdgcn_cvt_pkrtz(a, b));
}

// ---------------------------------------------------------------------------
// K0: prep. WthF = f16(W*g) in MFMA-fragment-coalesced layout (r12).
// colsum[p'] = sum of f16-rounded w; b2[p'] = bias + W·ln_beta.
// Block 0 inits y[b]=bl, c0acc=0.
// ---------------------------------------------------------------------------
__global__ __launch_bounds__(256) void prep_w(const float* __restrict__ Wq,
                        const float* __restrict__ Wk, const float* __restrict__ Wv,
                        const float* __restrict__ gq, const float* __restrict__ gk,
                        const float* __restrict__ gv,
                        const float* __restrict__ bnq, const float* __restrict__ bnk,
                        const float* __restrict__ bnv,
                        const float* __restrict__ bq, const float* __restrict__ bk,
                        const float* __restrict__ bv,
                        const float* __restrict__ bl,
                        half_t* __restrict__ WthF, float* __restrict__ colsum,
                        float* __restrict__ b2, float* __restrict__ y,
                        float* __restrict__ c0acc) {
    int pp = blockIdx.x;     // 192
    int which = pp >> 6, p = pp & 63;
    int ct = pp >> 4, c16 = pp & 15;
    const float* W  = (which == 0) ? Wq  : (which == 1) ? Wk  : Wv;
    const float* g  = (which == 0) ? gq  : (which == 1) ? gk  : gv;
    const float* bn = (which == 0) ? bnq : (which == 1) ? bnk : bnv;
    const float* bb = (which == 0) ? bq  : (which == 1) ? bk  : bv;
    int t = threadIdx.x;
    if (pp == 0) {
        if (t < 32) y[t] = bl[0];
        if (t == 32) c0acc[0] = 0.f;
    }
    float cs = 0.f, dt = 0.f;
    #pragma unroll
    for (int l = 0; l < 2; ++l) {
        int e = t + l * 256;
        float wv = W[p * E_DIM + e];
        half_t wh = (half_t)(wv * g[e]);
        int k32 = e >> 5, g2 = (e >> 3) & 3, j = e & 7;
        WthF[(((size_t)(ct * 16 + k32) * 64) + g2 * 16 + c16) * 8 + j] = wh;
        cs += (float)wh;
        dt += wv * bn[e];
    }
    cs = block_reduce_256(cs);
    __syncthreads();
    dt = block_reduce_256(dt);
    if (t == 0) { colsum[pp] = cs; b2[pp] = dt + bb[p]; }
}

// ---------------------------------------------------------------------------
// K1: blocks 0-1023: fused LN+QKV. q -> row layout; k -> KF (A-frag) + KTF
// (B-frag); v -> VTF (B-frag). Blocks 1024-1055: Wl2 via MFMA. Blocks
// 1056-1063: ones-row (col 8) of KTF/VTF. KTF/VTF cols 9-15 stay 0xAA
// poison (finite f16 garbage) -- feeds U-columns that are never read.
// ---------------------------------------------------------------------------
__global__ __launch_bounds__(256) void ln_qkv_wl2(const float* __restrict__ x,
                                              const half_t* __restrict__ WthF,
                                              const float* __restrict__ b2,
                                              const float* __restrict__ colsum,
                                              half_t* __restrict__ q16,
                                              half_t* __restrict__ KF,
                                              half_t* __restrict__ KTF,
                                              half_t* __restrict__ VTF,
                                              const float* __restrict__ Wl,
                                              const float* __restrict__ Wo,
                                              const float* __restrict__ bo,
                                              float* __restrict__ Wl2,
                                              float* __restrict__ c0acc) {
    __shared__ half_t Xs[16 * XS_STRIDE];
    __shared__ float stats[16][2];
    if (blockIdx.x < 1024) {
        const int t = threadIdx.x;
        const int lane = t & 63;
        const int w = t >> 6;
        const int g2 = lane >> 4, c16 = lane & 15;
        const int row0 = blockIdx.x * 16;
        {   // stage x -> f16 LDS, coalesced; LN stats on the fly
            const int row = t >> 4, c = t & 15;
            const float4* xrow = (const float4*)(x + (size_t)(row0 + row) * E_DIM);
            float sx = 0.f, sxx = 0.f;
            #pragma unroll
            for (int l = 0; l < 8; ++l) {
                int f4 = c + l * 16;
                float4 a = xrow[f4];
                sx  += a.x + a.y + a.z + a.w;
                sxx += a.x*a.x + a.y*a.y + a.z*a.z + a.w*a.w;
                half4v h;
                h[0] = (half_t)a.x; h[1] = (half_t)a.y;
                h[2] = (half_t)a.z; h[3] = (half_t)a.w;
                *(half4v*)&Xs[row * XS_STRIDE + f4 * 4] = h;
            }
            #pragma unroll
            for (int m = 1; m <= 8; m <<= 1) {
                sx += __shfl_xor(sx, m); sxx += __shfl_xor(sxx, m);
            }
            if (c == 0) {
                float mean = sx * (1.f / E_DIM);
                float var  = sxx * (1.f / E_DIM) - mean * mean;
                stats[row][0] = mean;
                stats[row][1] = rsqrtf(var + 1e-5f);
            }
        }
        __syncthreads();
        f32x4 acc[3] = {{0.f,0.f,0.f,0.f},{0.f,0.f,0.f,0.f},{0.f,0.f,0.f,0.f}};
        const half_t* wf = WthF + (size_t)w * 3 * 16 * 512;
        #pragma unroll 4
        for (int k32 = 0; k32 < 16; ++k32) {
            half8v af = *(const half8v*)&Xs[c16 * XS_STRIDE + k32 * 32 + g2 * 8];
            #pragma unroll
            for (int nt = 0; nt < 3; ++nt) {
                half8v bf = *(const half8v*)(wf + ((size_t)(nt * 16 + k32)) * 512 + lane * 8);
                acc[nt] = __builtin_amdgcn_mfma_f32_16x16x32_f16(af, bf, acc[nt], 0, 0, 0);
            }
        }
        #pragma unroll
        for (int nt = 0; nt < 3; ++nt) {
            int pp = w * 48 + nt * 16 + c16;
            float cs = colsum[pp], bb = b2[pp];
            int which = pp >> 6, p = pp & 63;
            int h = p >> 3, d = p & 7;
            #pragma unroll
            for (int r = 0; r < 4; ++r) {
                int rowi = g2 * 4 + r;
                float val = stats[rowi][1] * (acc[nt][r] - stats[rowi][0] * cs) + bb;
                int ng = row0 + rowi;
                int b = ng >> 9, n = ng & 511;
                int bh = b * H_DIM + h;
                half_t hv = (half_t)val;
                if (which == 0) {
                    q16[(((size_t)bh) * N_DIM + n) * D_DIM + d] = hv;
                } else if (which == 1) {
                    KF [((size_t)bh * 32 + (n >> 4)) * 128 + (n & 15) * 8 + d] = hv;
                    KTF[((size_t)bh * 16 + (n >> 5)) * 512
                        + (((n >> 3) & 3) * 16 + d) * 8 + (n & 7)] = hv;
                } else {
                    VTF[((size_t)bh * 16 + (n >> 5)) * 512
                        + (((n >> 3) & 3) * 16 + d) * 8 + (n & 7)] = hv;
                }
            }
        }
    } else if (blockIdx.x < 1056) {
        // ---- Wl2 MFMA: blk in [0,32) ----
        const int blk = blockIdx.x - 1024;
        const int t = threadIdx.x;
        const int lane = t & 63;
        const int w = t >> 6;
        const int g2 = lane >> 4, c16 = lane & 15;
        const int n0 = blk * 16;
        const int pcol = w * 16;
        f32x4 acc = {0.f, 0.f, 0.f, 0.f};
        float pc = 0.f;
        const float* arow = Wl + (size_t)(n0 + c16) * E_DIM;
        #pragma unroll 2
        for (int k0 = 0; k0 < E_DIM; k0 += 32) {
            int kbase = k0 + g2 * 8;
            float4 a0 = *(const float4*)(arow + kbase);
            float4 a1 = *(const float4*)(arow + kbase + 4);
            if (w == 0) {
                float4 b0 = *(const float4*)(bo + kbase);
                float4 b1 = *(const float4*)(bo + kbase + 4);
                pc += a0.x*b0.x + a0.y*b0.y + a0.z*b0.z + a0.w*b0.w
                    + a1.x*b1.x + a1.y*b1.y + a1.z*b1.z + a1.w*b1.w;
            }
            half8v af = cvt8(a0, a1);
            half8v bf;
            #pragma unroll
            for (int j = 0; j < 8; ++j)
                bf[j] = (half_t)Wo[(size_t)(kbase + j) * 64 + pcol + c16];
            acc = __builtin_amdgcn_mfma_f32_16x16x32_f16(af, bf, acc, 0, 0, 0);
        }
        int p = pcol + c16, h = p >> 3, d = p & 7;
        #pragma unroll
        for (int r = 0; r < 4; ++r) {
            int n = n0 + g2 * 4 + r;
            Wl2[h * (N_DIM * D_DIM) + n * D_DIM + d] = acc[r];
        }
        if (w == 0) {
            pc += __shfl_xor(pc, 16); pc += __shfl_xor(pc, 32);
            pc += __shfl_xor(pc, 1);  pc += __shfl_xor(pc, 2);
            pc += __shfl_xor(pc, 4);  pc += __shfl_xor(pc, 8);
            if (lane == 0) atomicAdd(c0acc, pc);
        }
    } else {
        // ---- ones-row writer: KTF/VTF col 8 = 1.0 ----
        int tid = (blockIdx.x - 1056) * 256 + threadIdx.x;   // 0..2047
        half8v ones;
        #pragma unroll
        for (int j = 0; j < 8; ++j) ones[j] = (half_t)1.f;
        for (int u = tid; u < 16384; u += 2048) {
            int bh = u >> 6, rem = u & 63, j32 = rem >> 2, g2 = rem & 3;
            size_t addr = ((size_t)(bh * 16 + j32)) * 512 + (g2 * 16 + 8) * 8;
            *(half8v*)&KTF[addr] = ones;
            *(half8v*)&VTF[addr] = ones;
        }
    }
}

// ---------------------------------------------------------------------------
// K2: MFMA Hopfield + fused classifier, global-fragment edition.
// Grid 2048 = 8 segs x 256 bh (bh = blockIdx&255 -> all segs of a bh on one
// XCD). Wave owns 16 rows; LDS only Xi (1 KB) + Pb (4.5 KB) -> 8 blocks/CU
// (thread-capped, 32 waves/CU). A-frags from KF (256 B coalesced, g2==0
// predicated), B-frags from KTF/VTF (1 KB coalesced). No K staging, no
// transpose, no barriers in the loop. launch_bounds(256,8) caps VGPR at 64
// (r9 relapse guard); #pragma unroll 1 on j32 blocks pipelining blowup.
// ---------------------------------------------------------------------------
__global__ __launch_bounds__(256, 8) void hopfield(const half_t* __restrict__ q16,
                                                   const half_t* __restrict__ KF,
                                                   const half_t* __restrict__ KTF,
                                                   const half_t* __restrict__ VTF,
                                                   const float* __restrict__ Wl2,
                                                   const float* __restrict__ c0acc,
                                                   float* __restrict__ y) {
    __shared__ half_t Xi[64 * 8];               // 1 KB
    __shared__ half_t Pb[4 * 16 * PB_STRIDE];   // 4.5 KB
    const int t = threadIdx.x;
    const int lane = t & 63;
    const int w = t >> 6;
    const int g2 = lane >> 4;
    const int c16 = lane & 15;
    const int bh = blockIdx.x & 255, seg = blockIdx.x >> 8;
    const float C = 0.25f * 1.44269504088896f;
    const half_t* qg  = q16 + ((size_t)bh * N_DIM + seg * 64) * D_DIM;
    const half_t* kfb = KF  + (size_t)bh * 4096;
    const half_t* ktb = KTF + (size_t)bh * 8192;
    const half_t* vtb = VTF + (size_t)bh * 8192;
    const float* wl2p = Wl2 + (bh & 7) * (N_DIM * D_DIM) + seg * 64 * 8;

    // stage Xi = C*q, wave-local (lanes 0-15 load 16 rows) -- no barrier
    if (lane < 16) {
        half8v hq = *(const half8v*)(qg + (w * 16 + lane) * 8);
        half8v h;
        #pragma unroll
        for (int d = 0; d < 8; ++d) h[d] = (half_t)(C * (float)hq[d]);
        *(half8v*)&Xi[(w * 16 + lane) * 8] = h;
    }
    half_t* myP = &Pb[w * 16 * PB_STRIDE];
    float fsum = 0.f;

    #pragma unroll 1
    for (int it = 0; it < 4; ++it) {
        const half_t* btf = (it < 3) ? ktb : vtb;
        half8v bxi = {};
        if (g2 == 0) bxi = *(const half8v*)&Xi[(w * 16 + c16) * 8];
        f32x4 U = {0.f, 0.f, 0.f, 0.f};
        #pragma unroll 1
        for (int j32 = 0; j32 < 16; ++j32) {
            half8v bKT = *(const half8v*)(btf + j32 * 512 + lane * 8);
            #pragma unroll
            for (int hh = 0; hh < 2; ++hh) {
                int jt16 = j32 * 2 + hh;
                half8v ak = {};
                if (g2 == 0) ak = *(const half8v*)(kfb + jt16 * 128 + c16 * 8);
                f32x4 S = {0.f, 0.f, 0.f, 0.f};
                S = __builtin_amdgcn_mfma_f32_16x16x32_f16(ak, bxi, S, 0, 0, 0);
                half2v lo = pk2(__builtin_amdgcn_exp2f(S[0]), __builtin_amdgcn_exp2f(S[1]));
                half2v hi = pk2(__builtin_amdgcn_exp2f(S[2]), __builtin_amdgcn_exp2f(S[3]));
                half4v p = __builtin_shufflevector(lo, hi, 0, 1, 2, 3);
                *(half4v*)&myP[c16 * PB_STRIDE + hh * 16 + g2 * 4] = p;
            }
            half4v alo = *(const half4v*)&myP[c16 * PB_STRIDE + g2 * 8];
            half4v ahi = *(const half4v*)&myP[c16 * PB_STRIDE + g2 * 8 + 4];
            half8v ap = __builtin_shufflevector(alo, ahi, 0, 1, 2, 3, 4, 5, 6, 7);
            U = __builtin_amdgcn_mfma_f32_16x16x32_f16(ap, bKT, U, 0, 0, 0);
        }
        int srcl = (lane & 48) | 8;   // lane holding col 8 (denominator)
        #pragma unroll
        for (int r = 0; r < 4; ++r) {
            float l0 = __shfl(U[r], srcl, 64);
            float inv = __builtin_amdgcn_rcpf(l0);
            if (c16 < 8) {
                int i0 = w * 16 + g2 * 4 + r;
                if (it < 3) {
                    Xi[i0 * 8 + c16] = (half_t)(U[r] * (C * inv));
                } else {
                    fsum += (U[r] * inv) * wl2p[i0 * 8 + c16];
                }
            }
        }
    }
    float tot = block_reduce_256(fsum);
    if (t == 0) atomicAdd(&y[bh >> 3], tot);
    if (blockIdx.x == 0 && t < 32) {
        atomicAdd(&y[t], c0acc[0]);
    }
}

// ---------------------------------------------------------------------------
extern "C" void kernel_launch(void* const* d_in, const int* in_sizes, int n_in,
                              void* d_out, int out_size, void* d_ws, size_t ws_size,
                              hipStream_t stream) {
    const float* x   = (const float*)d_in[0];
    const float* g_q = (const float*)d_in[1];
    const float* b_q = (const float*)d_in[2];
    const float* g_k = (const float*)d_in[3];
    const float* b_k = (const float*)d_in[4];
    const float* g_v = (const float*)d_in[5];
    const float* b_v = (const float*)d_in[6];
    const float* Wq  = (const float*)d_in[7];
    const float* bq  = (const float*)d_in[8];
    const float* Wk  = (const float*)d_in[9];
    const float* bk  = (const float*)d_in[10];
    const float* Wv  = (const float*)d_in[11];
    const float* bv  = (const float*)d_in[12];
    const float* Wo  = (const float*)d_in[13];
    const float* bo  = (const float*)d_in[14];
    const float* Wl  = (const float*)d_in[15];
    const float* bl  = (const float*)d_in[16];
    float* out = (float*)d_out;

    float* ws = (float*)d_ws;
    float*  colsum = ws;                       // 192
    float*  b2     = ws + 192;                 // 192
    float*  c0acc  = ws + 384;                 // 1 (+pad to 64)
    float*  Wl2    = ws + 448;                 // 32768
    half_t* WthF   = (half_t*)(ws + 33216);    // 98304 halves  = 49152 f
    half_t* q16    = (half_t*)(ws + 82368);    // 1048576 halves = 524288 f
    half_t* KF     = (half_t*)(ws + 606656);   // 1048576 halves = 524288 f
    half_t* KTF    = (half_t*)(ws + 1130944);  // 2097152 halves = 1048576 f
    half_t* VTF    = (half_t*)(ws + 2179520);  // 2097152 halves = 1048576 f

    prep_w    <<<192, 256, 0, stream>>>(Wq, Wk, Wv, g_q, g_k, g_v,
                                        b_q, b_k, b_v, bq, bk, bv, bl,
                                        WthF, colsum, b2, out, c0acc);
    ln_qkv_wl2<<<1064, 256, 0, stream>>>(x, WthF, b2, colsum, q16, KF, KTF, VTF,
                                         Wl, Wo, bo, Wl2, c0acc);
    hopfield  <<<2048, 256, 0, stream>>>(q16, KF, KTF, VTF, Wl2, c0acc, out);
}

// Round 14
// 172.617 us; speedup vs baseline: 1.0291x; 1.0291x over previous
//
#include <hip/hip_runtime.h>

#define E_DIM 512
#define N_DIM 512
#define B_DIM 32
#define H_DIM 8
#define D_DIM 8
#define P3    192   // 3 * H * D

typedef _Float16 half_t;
typedef __attribute__((ext_vector_type(2))) _Float16 half2v;
typedef __attribute__((ext_vector_type(4))) _Float16 half4v;
typedef __attribute__((ext_vector_type(8))) _Float16 half8v;
typedef __attribute__((ext_vector_type(4))) float f32x4;

#define PB_STRIDE 36   // hopfield P-scratch stride
#define XS_STRIDE 520  // ln x-tile stride (halves)

// ---------------------------------------------------------------------------
__device__ inline float block_reduce_256(float v) {
    __shared__ float red[4];
    #pragma unroll
    for (int m = 32; m >= 1; m >>= 1) v += __shfl_xor(v, m);
    int w = threadIdx.x >> 6;
    if ((threadIdx.x & 63) == 0) red[w] = v;
    __syncthreads();
    if (threadIdx.x == 0) v = red[0] + red[1] + red[2] + red[3];
    return v;
}

__device__ inline half8v cvt8(float4 a, float4 b) {
    half8v h;
    h[0] = (half_t)a.x; h[1] = (half_t)a.y; h[2] = (half_t)a.z; h[3] = (half_t)a.w;
    h[4] = (half_t)b.x; h[5] = (half_t)b.y; h[6] = (half_t)b.z; h[7] = (half_t)b.w;
    return h;
}

__device__ inline half2v pk2(float a, float b) {
    return __builtin_bit_cast(half2v, __builtin_amdgcn_cvt_pkrtz(a, b));
}

// ---------------------------------------------------------------------------
// K0: prep. WthF = f16(W*g) in MFMA-fragment-coalesced layout (r12).
// colsum[p'] = sum of f16-rounded w; b2[p'] = bias + W·ln_beta.
// Block 0 inits y[b]=bl, c0acc=0.
// ---------------------------------------------------------------------------
__global__ __launch_bounds__(256) void prep_w(const float* __restrict__ Wq,
                        const float* __restrict__ Wk, const float* __restrict__ Wv,
                        const float* __restrict__ gq, const float* __restrict__ gk,
                        const float* __restrict__ gv,
                        const float* __restrict__ bnq, const float* __restrict__ bnk,
                        const float* __restrict__ bnv,
                        const float* __restrict__ bq, const float* __restrict__ bk,
                        const float* __restrict__ bv,
                        const float* __restrict__ bl,
                        half_t* __restrict__ WthF, float* __restrict__ colsum,
                        float* __restrict__ b2, float* __restrict__ y,
                        float* __restrict__ c0acc) {
    int pp = blockIdx.x;     // 192
    int which = pp >> 6, p = pp & 63;
    int ct = pp >> 4, c16 = pp & 15;
    const float* W  = (which == 0) ? Wq  : (which == 1) ? Wk  : Wv;
    const float* g  = (which == 0) ? gq  : (which == 1) ? gk  : gv;
    const float* bn = (which == 0) ? bnq : (which == 1) ? bnk : bnv;
    const float* bb = (which == 0) ? bq  : (which == 1) ? bk  : bv;
    int t = threadIdx.x;
    if (pp == 0) {
        if (t < 32) y[t] = bl[0];
        if (t == 32) c0acc[0] = 0.f;
    }
    float cs = 0.f, dt = 0.f;
    #pragma unroll
    for (int l = 0; l < 2; ++l) {
        int e = t + l * 256;
        float wv = W[p * E_DIM + e];
        half_t wh = (half_t)(wv * g[e]);
        int k32 = e >> 5, g2 = (e >> 3) & 3, j = e & 7;
        WthF[(((size_t)(ct * 16 + k32) * 64) + g2 * 16 + c16) * 8 + j] = wh;
        cs += (float)wh;
        dt += wv * bn[e];
    }
    cs = block_reduce_256(cs);
    __syncthreads();
    dt = block_reduce_256(dt);
    if (t == 0) { colsum[pp] = cs; b2[pp] = dt + bb[p]; }
}

// ---------------------------------------------------------------------------
// K1: blocks 0-1023: fused LN+QKV. q -> row layout; k -> KF (A-frag) + KTF
// (B-frag); v -> VTF (B-frag). Blocks 1024-1055: Wl2 via MFMA. Blocks
// 1056-1063: ones-row (col 8) of KTF/VTF. (verbatim r13)
// ---------------------------------------------------------------------------
__global__ __launch_bounds__(256) void ln_qkv_wl2(const float* __restrict__ x,
                                              const half_t* __restrict__ WthF,
                                              const float* __restrict__ b2,
                                              const float* __restrict__ colsum,
                                              half_t* __restrict__ q16,
                                              half_t* __restrict__ KF,
                                              half_t* __restrict__ KTF,
                                              half_t* __restrict__ VTF,
                                              const float* __restrict__ Wl,
                                              const float* __restrict__ Wo,
                                              const float* __restrict__ bo,
                                              float* __restrict__ Wl2,
                                              float* __restrict__ c0acc) {
    __shared__ half_t Xs[16 * XS_STRIDE];
    __shared__ float stats[16][2];
    if (blockIdx.x < 1024) {
        const int t = threadIdx.x;
        const int lane = t & 63;
        const int w = t >> 6;
        const int g2 = lane >> 4, c16 = lane & 15;
        const int row0 = blockIdx.x * 16;
        {   // stage x -> f16 LDS, coalesced; LN stats on the fly
            const int row = t >> 4, c = t & 15;
            const float4* xrow = (const float4*)(x + (size_t)(row0 + row) * E_DIM);
            float sx = 0.f, sxx = 0.f;
            #pragma unroll
            for (int l = 0; l < 8; ++l) {
                int f4 = c + l * 16;
                float4 a = xrow[f4];
                sx  += a.x + a.y + a.z + a.w;
                sxx += a.x*a.x + a.y*a.y + a.z*a.z + a.w*a.w;
                half4v h;
                h[0] = (half_t)a.x; h[1] = (half_t)a.y;
                h[2] = (half_t)a.z; h[3] = (half_t)a.w;
                *(half4v*)&Xs[row * XS_STRIDE + f4 * 4] = h;
            }
            #pragma unroll
            for (int m = 1; m <= 8; m <<= 1) {
                sx += __shfl_xor(sx, m); sxx += __shfl_xor(sxx, m);
            }
            if (c == 0) {
                float mean = sx * (1.f / E_DIM);
                float var  = sxx * (1.f / E_DIM) - mean * mean;
                stats[row][0] = mean;
                stats[row][1] = rsqrtf(var + 1e-5f);
            }
        }
        __syncthreads();
        f32x4 acc[3] = {{0.f,0.f,0.f,0.f},{0.f,0.f,0.f,0.f},{0.f,0.f,0.f,0.f}};
        const half_t* wf = WthF + (size_t)w * 3 * 16 * 512;
        #pragma unroll 4
        for (int k32 = 0; k32 < 16; ++k32) {
            half8v af = *(const half8v*)&Xs[c16 * XS_STRIDE + k32 * 32 + g2 * 8];
            #pragma unroll
            for (int nt = 0; nt < 3; ++nt) {
                half8v bf = *(const half8v*)(wf + ((size_t)(nt * 16 + k32)) * 512 + lane * 8);
                acc[nt] = __builtin_amdgcn_mfma_f32_16x16x32_f16(af, bf, acc[nt], 0, 0, 0);
            }
        }
        #pragma unroll
        for (int nt = 0; nt < 3; ++nt) {
            int pp = w * 48 + nt * 16 + c16;
            float cs = colsum[pp], bb = b2[pp];
            int which = pp >> 6, p = pp & 63;
            int h = p >> 3, d = p & 7;
            #pragma unroll
            for (int r = 0; r < 4; ++r) {
                int rowi = g2 * 4 + r;
                float val = stats[rowi][1] * (acc[nt][r] - stats[rowi][0] * cs) + bb;
                int ng = row0 + rowi;
                int b = ng >> 9, n = ng & 511;
                int bh = b * H_DIM + h;
                half_t hv = (half_t)val;
                if (which == 0) {
                    q16[(((size_t)bh) * N_DIM + n) * D_DIM + d] = hv;
                } else if (which == 1) {
                    KF [((size_t)bh * 32 + (n >> 4)) * 128 + (n & 15) * 8 + d] = hv;
                    KTF[((size_t)bh * 16 + (n >> 5)) * 512
                        + (((n >> 3) & 3) * 16 + d) * 8 + (n & 7)] = hv;
                } else {
                    VTF[((size_t)bh * 16 + (n >> 5)) * 512
                        + (((n >> 3) & 3) * 16 + d) * 8 + (n & 7)] = hv;
                }
            }
        }
    } else if (blockIdx.x < 1056) {
        // ---- Wl2 MFMA: blk in [0,32) ----
        const int blk = blockIdx.x - 1024;
        const int t = threadIdx.x;
        const int lane = t & 63;
        const int w = t >> 6;
        const int g2 = lane >> 4, c16 = lane & 15;
        const int n0 = blk * 16;
        const int pcol = w * 16;
        f32x4 acc = {0.f, 0.f, 0.f, 0.f};
        float pc = 0.f;
        const float* arow = Wl + (size_t)(n0 + c16) * E_DIM;
        #pragma unroll 2
        for (int k0 = 0; k0 < E_DIM; k0 += 32) {
            int kbase = k0 + g2 * 8;
            float4 a0 = *(const float4*)(arow + kbase);
            float4 a1 = *(const float4*)(arow + kbase + 4);
            if (w == 0) {
                float4 b0 = *(const float4*)(bo + kbase);
                float4 b1 = *(const float4*)(bo + kbase + 4);
                pc += a0.x*b0.x + a0.y*b0.y + a0.z*b0.z + a0.w*b0.w
                    + a1.x*b1.x + a1.y*b1.y + a1.z*b1.z + a1.w*b1.w;
            }
            half8v af = cvt8(a0, a1);
            half8v bf;
            #pragma unroll
            for (int j = 0; j < 8; ++j)
                bf[j] = (half_t)Wo[(size_t)(kbase + j) * 64 + pcol + c16];
            acc = __builtin_amdgcn_mfma_f32_16x16x32_f16(af, bf, acc, 0, 0, 0);
        }
        int p = pcol + c16, h = p >> 3, d = p & 7;
        #pragma unroll
        for (int r = 0; r < 4; ++r) {
            int n = n0 + g2 * 4 + r;
            Wl2[h * (N_DIM * D_DIM) + n * D_DIM + d] = acc[r];
        }
        if (w == 0) {
            pc += __shfl_xor(pc, 16); pc += __shfl_xor(pc, 32);
            pc += __shfl_xor(pc, 1);  pc += __shfl_xor(pc, 2);
            pc += __shfl_xor(pc, 4);  pc += __shfl_xor(pc, 8);
            if (lane == 0) atomicAdd(c0acc, pc);
        }
    } else {
        // ---- ones-row writer: KTF/VTF col 8 = 1.0 ----
        int tid = (blockIdx.x - 1056) * 256 + threadIdx.x;   // 0..2047
        half8v ones;
        #pragma unroll
        for (int j = 0; j < 8; ++j) ones[j] = (half_t)1.f;
        for (int u = tid; u < 16384; u += 2048) {
            int bh = u >> 6, rem = u & 63, j32 = rem >> 2, g2 = rem & 3;
            size_t addr = ((size_t)(bh * 16 + j32)) * 512 + (g2 * 16 + 8) * 8;
            *(half8v*)&KTF[addr] = ones;
            *(half8v*)&VTF[addr] = ones;
        }
    }
}

// ---------------------------------------------------------------------------
// K2: MFMA Hopfield, global-fragment + MANUAL SOFTWARE PIPELINE.
// r13 post-mortem: VGPR 24 + unroll 1 = zero ILP -> every j32 serially eats
// 2x L2 latency (dur 50->65 despite occupancy 70%). Fix: prefetch next
// j32's bKT + 2 ak fragments before computing current (adds ~28 VGPR, cap
// 64 via launch_bounds(256,8); WRITE_SIZE is the spill tripwire).
// ---------------------------------------------------------------------------
__global__ __launch_bounds__(256, 8) void hopfield(const half_t* __restrict__ q16,
                                                   const half_t* __restrict__ KF,
                                                   const half_t* __restrict__ KTF,
                                                   const half_t* __restrict__ VTF,
                                                   const float* __restrict__ Wl2,
                                                   const float* __restrict__ c0acc,
                                                   float* __restrict__ y) {
    __shared__ half_t Xi[64 * 8];               // 1 KB
    __shared__ half_t Pb[4 * 16 * PB_STRIDE];   // 4.5 KB
    const int t = threadIdx.x;
    const int lane = t & 63;
    const int w = t >> 6;
    const int g2 = lane >> 4;
    const int c16 = lane & 15;
    const int bh = blockIdx.x & 255, seg = blockIdx.x >> 8;
    const float C = 0.25f * 1.44269504088896f;
    const half_t* qg  = q16 + ((size_t)bh * N_DIM + seg * 64) * D_DIM;
    const half_t* kfb = KF  + (size_t)bh * 4096;
    const half_t* ktb = KTF + (size_t)bh * 8192;
    const half_t* vtb = VTF + (size_t)bh * 8192;
    const float* wl2p = Wl2 + (bh & 7) * (N_DIM * D_DIM) + seg * 64 * 8;

    if (lane < 16) {   // stage Xi = C*q, wave-local — no barrier
        half8v hq = *(const half8v*)(qg + (w * 16 + lane) * 8);
        half8v h;
        #pragma unroll
        for (int d = 0; d < 8; ++d) h[d] = (half_t)(C * (float)hq[d]);
        *(half8v*)&Xi[(w * 16 + lane) * 8] = h;
    }
    half_t* myP = &Pb[w * 16 * PB_STRIDE];
    float fsum = 0.f;

    #pragma unroll 1
    for (int it = 0; it < 4; ++it) {
        const half_t* btf = (it < 3) ? ktb : vtb;
        half8v bxi = {};
        if (g2 == 0) bxi = *(const half8v*)&Xi[(w * 16 + c16) * 8];
        f32x4 U = {0.f, 0.f, 0.f, 0.f};
        // prime the pipeline: j32 = 0 fragments
        half8v nbKT = *(const half8v*)(btf + lane * 8);
        half8v nak0 = {}, nak1 = {};
        if (g2 == 0) {
            nak0 = *(const half8v*)(kfb + c16 * 8);
            nak1 = *(const half8v*)(kfb + 128 + c16 * 8);
        }
        #pragma unroll 1
        for (int j32 = 0; j32 < 16; ++j32) {
            half8v bKT = nbKT, ak0 = nak0, ak1 = nak1;
            if (j32 < 15) {   // prefetch j32+1 (off the critical path)
                nbKT = *(const half8v*)(btf + (j32 + 1) * 512 + lane * 8);
                if (g2 == 0) {
                    nak0 = *(const half8v*)(kfb + (j32 * 2 + 2) * 128 + c16 * 8);
                    nak1 = *(const half8v*)(kfb + (j32 * 2 + 3) * 128 + c16 * 8);
                }
            }
            {
                f32x4 S = {0.f, 0.f, 0.f, 0.f};
                S = __builtin_amdgcn_mfma_f32_16x16x32_f16(ak0, bxi, S, 0, 0, 0);
                half2v lo = pk2(__builtin_amdgcn_exp2f(S[0]), __builtin_amdgcn_exp2f(S[1]));
                half2v hi = pk2(__builtin_amdgcn_exp2f(S[2]), __builtin_amdgcn_exp2f(S[3]));
                half4v p = __builtin_shufflevector(lo, hi, 0, 1, 2, 3);
                *(half4v*)&myP[c16 * PB_STRIDE + g2 * 4] = p;
            }
            {
                f32x4 S = {0.f, 0.f, 0.f, 0.f};
                S = __builtin_amdgcn_mfma_f32_16x16x32_f16(ak1, bxi, S, 0, 0, 0);
                half2v lo = pk2(__builtin_amdgcn_exp2f(S[0]), __builtin_amdgcn_exp2f(S[1]));
                half2v hi = pk2(__builtin_amdgcn_exp2f(S[2]), __builtin_amdgcn_exp2f(S[3]));
                half4v p = __builtin_shufflevector(lo, hi, 0, 1, 2, 3);
                *(half4v*)&myP[c16 * PB_STRIDE + 16 + g2 * 4] = p;
            }
            half4v alo = *(const half4v*)&myP[c16 * PB_STRIDE + g2 * 8];
            half4v ahi = *(const half4v*)&myP[c16 * PB_STRIDE + g2 * 8 + 4];
            half8v ap = __builtin_shufflevector(alo, ahi, 0, 1, 2, 3, 4, 5, 6, 7);
            U = __builtin_amdgcn_mfma_f32_16x16x32_f16(ap, bKT, U, 0, 0, 0);
        }
        int srcl = (lane & 48) | 8;   // lane holding col 8 (denominator)
        #pragma unroll
        for (int r = 0; r < 4; ++r) {
            float l0 = __shfl(U[r], srcl, 64);
            float inv = __builtin_amdgcn_rcpf(l0);
            if (c16 < 8) {
                int i0 = w * 16 + g2 * 4 + r;
                if (it < 3) {
                    Xi[i0 * 8 + c16] = (half_t)(U[r] * (C * inv));
                } else {
                    fsum += (U[r] * inv) * wl2p[i0 * 8 + c16];
                }
            }
        }
    }
    float tot = block_reduce_256(fsum);
    if (t == 0) atomicAdd(&y[bh >> 3], tot);
    if (blockIdx.x == 0 && t < 32) {
        atomicAdd(&y[t], c0acc[0]);
    }
}

// ---------------------------------------------------------------------------
extern "C" void kernel_launch(void* const* d_in, const int* in_sizes, int n_in,
                              void* d_out, int out_size, void* d_ws, size_t ws_size,
                              hipStream_t stream) {
    const float* x   = (const float*)d_in[0];
    const float* g_q = (const float*)d_in[1];
    const float* b_q = (const float*)d_in[2];
    const float* g_k = (const float*)d_in[3];
    const float* b_k = (const float*)d_in[4];
    const float* g_v = (const float*)d_in[5];
    const float* b_v = (const float*)d_in[6];
    const float* Wq  = (const float*)d_in[7];
    const float* bq  = (const float*)d_in[8];
    const float* Wk  = (const float*)d_in[9];
    const float* bk  = (const float*)d_in[10];
    const float* Wv  = (const float*)d_in[11];
    const float* bv  = (const float*)d_in[12];
    const float* Wo  = (const float*)d_in[13];
    const float* bo  = (const float*)d_in[14];
    const float* Wl  = (const float*)d_in[15];
    const float* bl  = (const float*)d_in[16];
    float* out = (float*)d_out;

    float* ws = (float*)d_ws;
    float*  colsum = ws;                       // 192
    float*  b2     = ws + 192;                 // 192
    float*  c0acc  = ws + 384;                 // 1 (+pad to 64)
    float*  Wl2    = ws + 448;                 // 32768
    half_t* WthF   = (half_t*)(ws + 33216);    // 98304 halves  = 49152 f
    half_t* q16    = (half_t*)(ws + 82368);    // 1048576 halves = 524288 f
    half_t* KF     = (half_t*)(ws + 606656);   // 1048576 halves = 524288 f
    half_t* KTF    = (half_t*)(ws + 1130944);  // 2097152 halves = 1048576 f
    half_t* VTF    = (half_t*)(ws + 2179520);  // 2097152 halves = 1048576 f

    prep_w    <<<192, 256, 0, stream>>>(Wq, Wk, Wv, g_q, g_k, g_v,
                                        b_q, b_k, b_v, bq, bk, bv, bl,
                                        WthF, colsum, b2, out, c0acc);
    ln_qkv_wl2<<<1064, 256, 0, stream>>>(x, WthF, b2, colsum, q16, KF, KTF, VTF,
                                         Wl, Wo, bo, Wl2, c0acc);
    hopfield  <<<2048, 256, 0, stream>>>(q16, KF, KTF, VTF, Wl2, c0acc, out);
}

// Round 15
// 164.397 us; speedup vs baseline: 1.0805x; 1.0500x over previous
//
#include <hip/hip_runtime.h>

#define E_DIM 512
#define N_DIM 512
#define B_DIM 32
#define H_DIM 8
#define D_DIM 8
#define P3    192   // 3 * H * D

typedef _Float16 half_t;
typedef __attribute__((ext_vector_type(2))) _Float16 half2v;
typedef __attribute__((ext_vector_type(4))) _Float16 half4v;
typedef __attribute__((ext_vector_type(8))) _Float16 half8v;
typedef __attribute__((ext_vector_type(4))) float f32x4;

#define PB_STRIDE 36   // hopfield P-scratch stride
#define XS_STRIDE 520  // ln x-tile stride (halves): 260 dw % 32 = 4 -> uniform banks

// ---------------------------------------------------------------------------
__device__ inline float block_reduce_256(float v) {
    __shared__ float red[4];
    #pragma unroll
    for (int m = 32; m >= 1; m >>= 1) v += __shfl_xor(v, m);
    int w = threadIdx.x >> 6;
    if ((threadIdx.x & 63) == 0) red[w] = v;
    __syncthreads();
    if (threadIdx.x == 0) v = red[0] + red[1] + red[2] + red[3];
    return v;
}

__device__ inline half8v cvt8(float4 a, float4 b) {
    half8v h;
    h[0] = (half_t)a.x; h[1] = (half_t)a.y; h[2] = (half_t)a.z; h[3] = (half_t)a.w;
    h[4] = (half_t)b.x; h[5] = (half_t)b.y; h[6] = (half_t)b.z; h[7] = (half_t)b.w;
    return h;
}

__device__ inline half2v pk2(float a, float b) {
    return __builtin_bit_cast(half2v, __builtin_amdgcn_cvt_pkrtz(a, b));
}

// ---------------------------------------------------------------------------
// K0: prep. WthF = f16(W*g) in MFMA-fragment-coalesced layout:
//   WthF[((ct*16 + k32)*64 + g2*16 + c16)*8 + j] = Wth[p'=ct*16+c16][e=k32*32+g2*8+j]
// so ln_qkv's B-fragment load is WthF + (ct*16+k32)*512 + lane*8 (contiguous).
// colsum[p'] = sum of f16-rounded w; b2[p'] = bias + W·ln_beta.
// Block 0 inits y[b]=bl, c0acc=0.
// ---------------------------------------------------------------------------
__global__ __launch_bounds__(256) void prep_w(const float* __restrict__ Wq,
                        const float* __restrict__ Wk, const float* __restrict__ Wv,
                        const float* __restrict__ gq, const float* __restrict__ gk,
                        const float* __restrict__ gv,
                        const float* __restrict__ bnq, const float* __restrict__ bnk,
                        const float* __restrict__ bnv,
                        const float* __restrict__ bq, const float* __restrict__ bk,
                        const float* __restrict__ bv,
                        const float* __restrict__ bl,
                        half_t* __restrict__ WthF, float* __restrict__ colsum,
                        float* __restrict__ b2, float* __restrict__ y,
                        float* __restrict__ c0acc) {
    int pp = blockIdx.x;     // 192
    int which = pp >> 6, p = pp & 63;
    int ct = pp >> 4, c16 = pp & 15;
    const float* W  = (which == 0) ? Wq  : (which == 1) ? Wk  : Wv;
    const float* g  = (which == 0) ? gq  : (which == 1) ? gk  : gv;
    const float* bn = (which == 0) ? bnq : (which == 1) ? bnk : bnv;
    const float* bb = (which == 0) ? bq  : (which == 1) ? bk  : bv;
    int t = threadIdx.x;
    if (pp == 0) {
        if (t < 32) y[t] = bl[0];
        if (t == 32) c0acc[0] = 0.f;
    }
    float cs = 0.f, dt = 0.f;
    #pragma unroll
    for (int l = 0; l < 2; ++l) {
        int e = t + l * 256;
        float wv = W[p * E_DIM + e];
        half_t wh = (half_t)(wv * g[e]);
        int k32 = e >> 5, g2 = (e >> 3) & 3, j = e & 7;
        WthF[(((size_t)(ct * 16 + k32) * 64) + g2 * 16 + c16) * 8 + j] = wh;
        cs += (float)wh;
        dt += wv * bn[e];
    }
    cs = block_reduce_256(cs);
    __syncthreads();
    dt = block_reduce_256(dt);
    if (t == 0) { colsum[pp] = cs; b2[pp] = dt + bb[p]; }
}

// ---------------------------------------------------------------------------
// K1: blocks 0-1023: fused LN+QKV with LDS-staged x (coalesced loads) and
// coalesced WthF B-fragments. One barrier. Blocks 1024-1055: Wl2 via MFMA.
// ---------------------------------------------------------------------------
__global__ __launch_bounds__(256) void ln_qkv_wl2(const float* __restrict__ x,
                                              const half_t* __restrict__ WthF,
                                              const float* __restrict__ b2,
                                              const float* __restrict__ colsum,
                                              half_t* __restrict__ qkv16,
                                              const float* __restrict__ Wl,
                                              const float* __restrict__ Wo,
                                              const float* __restrict__ bo,
                                              float* __restrict__ Wl2,
                                              float* __restrict__ c0acc) {
    __shared__ half_t Xs[16 * XS_STRIDE];   // 16.25 KB
    __shared__ float stats[16][2];
    if (blockIdx.x < 1024) {
        const int t = threadIdx.x;
        const int lane = t & 63;
        const int w = t >> 6;
        const int g2 = lane >> 4, c16 = lane & 15;
        const int row0 = blockIdx.x * 16;
        // ---- stage x -> f16 LDS (coalesced: 16-lane groups read 256B runs) ----
        {
            const int row = t >> 4, c = t & 15;
            const float4* xrow = (const float4*)(x + (size_t)(row0 + row) * E_DIM);
            float sx = 0.f, sxx = 0.f;
            #pragma unroll
            for (int l = 0; l < 8; ++l) {
                int f4 = c + l * 16;
                float4 a = xrow[f4];
                sx  += a.x + a.y + a.z + a.w;
                sxx += a.x*a.x + a.y*a.y + a.z*a.z + a.w*a.w;
                half4v h;
                h[0] = (half_t)a.x; h[1] = (half_t)a.y;
                h[2] = (half_t)a.z; h[3] = (half_t)a.w;
                *(half4v*)&Xs[row * XS_STRIDE + f4 * 4] = h;
            }
            #pragma unroll
            for (int m = 1; m <= 8; m <<= 1) {
                sx += __shfl_xor(sx, m); sxx += __shfl_xor(sxx, m);
            }
            if (c == 0) {
                float mean = sx * (1.f / E_DIM);
                float var  = sxx * (1.f / E_DIM) - mean * mean;
                stats[row][0] = mean;
                stats[row][1] = rsqrtf(var + 1e-5f);
            }
        }
        __syncthreads();
        // ---- K-loop: A from LDS, B from WthF (lane-contiguous) ----
        f32x4 acc[3] = {{0.f,0.f,0.f,0.f},{0.f,0.f,0.f,0.f},{0.f,0.f,0.f,0.f}};
        const half_t* wf = WthF + (size_t)w * 3 * 16 * 512;
        #pragma unroll 4
        for (int k32 = 0; k32 < 16; ++k32) {
            half8v af = *(const half8v*)&Xs[c16 * XS_STRIDE + k32 * 32 + g2 * 8];
            #pragma unroll
            for (int nt = 0; nt < 3; ++nt) {
                half8v bf = *(const half8v*)(wf + ((size_t)(nt * 16 + k32)) * 512 + lane * 8);
                acc[nt] = __builtin_amdgcn_mfma_f32_16x16x32_f16(af, bf, acc[nt], 0, 0, 0);
            }
        }
        // ---- epilogue: LN correction + scattered f16 stores ----
        #pragma unroll
        for (int nt = 0; nt < 3; ++nt) {
            int pp = w * 48 + nt * 16 + c16;
            float cs = colsum[pp], bb = b2[pp];
            int which = pp >> 6, p = pp & 63;
            int h = p >> 3, d = p & 7;
            half_t* dst0 = qkv16 + (size_t)which * (B_DIM * H_DIM * N_DIM * D_DIM);
            #pragma unroll
            for (int r = 0; r < 4; ++r) {
                int rowi = g2 * 4 + r;
                float val = stats[rowi][1] * (acc[nt][r] - stats[rowi][0] * cs) + bb;
                int ng = row0 + rowi;
                int b = ng >> 9, n = ng & 511;
                dst0[(((size_t)(b * H_DIM + h)) * N_DIM + n) * D_DIM + d] = (half_t)val;
            }
        }
    } else {
        // ---- Wl2 MFMA: blk in [0,32) ----
        const int blk = blockIdx.x - 1024;
        const int t = threadIdx.x;
        const int lane = t & 63;
        const int w = t >> 6;
        const int g2 = lane >> 4, c16 = lane & 15;
        const int n0 = blk * 16;
        const int pcol = w * 16;
        f32x4 acc = {0.f, 0.f, 0.f, 0.f};
        float pc = 0.f;
        const float* arow = Wl + (size_t)(n0 + c16) * E_DIM;
        #pragma unroll 2
        for (int k0 = 0; k0 < E_DIM; k0 += 32) {
            int kbase = k0 + g2 * 8;
            float4 a0 = *(const float4*)(arow + kbase);
            float4 a1 = *(const float4*)(arow + kbase + 4);
            if (w == 0) {
                float4 b0 = *(const float4*)(bo + kbase);
                float4 b1 = *(const float4*)(bo + kbase + 4);
                pc += a0.x*b0.x + a0.y*b0.y + a0.z*b0.z + a0.w*b0.w
                    + a1.x*b1.x + a1.y*b1.y + a1.z*b1.z + a1.w*b1.w;
            }
            half8v af = cvt8(a0, a1);
            half8v bf;
            #pragma unroll
            for (int j = 0; j < 8; ++j)
                bf[j] = (half_t)Wo[(size_t)(kbase + j) * 64 + pcol + c16];
            acc = __builtin_amdgcn_mfma_f32_16x16x32_f16(af, bf, acc, 0, 0, 0);
        }
        int p = pcol + c16, h = p >> 3, d = p & 7;
        #pragma unroll
        for (int r = 0; r < 4; ++r) {
            int n = n0 + g2 * 4 + r;
            Wl2[h * (N_DIM * D_DIM) + n * D_DIM + d] = acc[r];
        }
        if (w == 0) {
            pc += __shfl_xor(pc, 16); pc += __shfl_xor(pc, 32);
            pc += __shfl_xor(pc, 1);  pc += __shfl_xor(pc, 2);
            pc += __shfl_xor(pc, 4);  pc += __shfl_xor(pc, 8);
            if (lane == 0) atomicAdd(c0acc, pc);
        }
    }
}

// ---------------------------------------------------------------------------
// K2: MFMA Hopfield + fused classifier — round-11/12 body (best measured:
// 50.2 us, VGPR 56, LDS 31.3 KB). Grid 1024 (4 blocks/CU). Kept verbatim:
// r13 (global fragments, occupancy 70%) and r14 (manual prefetch) both
// regressed to 61-65 us — off-LDS K-operands are L2-latency-bound in this
// short loop body; LDS staging is the proven optimum.
// ---------------------------------------------------------------------------
__global__ __launch_bounds__(256) void hopfield(const half_t* __restrict__ q16,
                                                const half_t* __restrict__ k16,
                                                const half_t* __restrict__ v16,
                                                const float* __restrict__ Wl2,
                                                const float* __restrict__ c0acc,
                                                float* __restrict__ y) {
    __shared__ half_t Kb[N_DIM * 8];
    __shared__ half_t Xi[128 * 8];
    __shared__ half_t KTb[16 * 536];
    __shared__ half_t Pb[4 * 16 * PB_STRIDE];
    const int t = threadIdx.x;
    const int lane = t & 63;
    const int w = t >> 6;
    const int g2 = lane >> 4;
    const int c16 = lane & 15;
    const int bh = blockIdx.x >> 2, seg = blockIdx.x & 3;
    const float C = 0.25f * 1.44269504088896f;
    const half_t* kg = k16 + (size_t)bh * (N_DIM * D_DIM);
    const half_t* vg = v16 + (size_t)bh * (N_DIM * D_DIM);
    const half_t* qg = q16 + (size_t)bh * (N_DIM * D_DIM) + seg * 128 * 8;
    const float* wl2p = Wl2 + (bh & 7) * (N_DIM * D_DIM) + seg * 128 * 8;

    for (int i = t; i < 536; i += 256) KTb[9 * 536 + i] = (half_t)0.f;
    {   // stage K rows + K^T + ones row
        int j0 = 2 * t;
        half8v r0 = *(const half8v*)(kg + j0 * 8);
        half8v r1 = *(const half8v*)(kg + j0 * 8 + 8);
        *(half8v*)&Kb[j0 * 8] = r0;
        *(half8v*)&Kb[j0 * 8 + 8] = r1;
        #pragma unroll
        for (int d = 0; d < 8; ++d) {
            KTb[d * 536 + j0] = r0[d];
            KTb[d * 536 + j0 + 1] = r1[d];
        }
        KTb[8 * 536 + j0] = (half_t)1.f;
        KTb[8 * 536 + j0 + 1] = (half_t)1.f;
    }
    if (t < 128) {   // stage Xi = C * q
        half8v hq = *(const half8v*)(qg + t * 8);
        half8v h;
        #pragma unroll
        for (int d = 0; d < 8; ++d) h[d] = (half_t)(C * (float)hq[d]);
        *(half8v*)&Xi[t * 8] = h;
    }
    __syncthreads();

    const half_t* zsrc = &KTb[9 * 536];
    half_t* myP = &Pb[w * 16 * PB_STRIDE];
    float fsum = 0.f;

    for (int it = 0; it < 4; ++it) {
        if (it == 3) {   // swap KTb rows 0-7 to V^T
            __syncthreads();
            int j0 = 2 * t;
            half8v r0 = *(const half8v*)(vg + j0 * 8);
            half8v r1 = *(const half8v*)(vg + j0 * 8 + 8);
            #pragma unroll
            for (int d = 0; d < 8; ++d) {
                KTb[d * 536 + j0] = r0[d];
                KTb[d * 536 + j0 + 1] = r1[d];
            }
            __syncthreads();
        }
        const half_t* x0p = (g2 == 0) ? &Xi[(w * 32 + c16) * 8] : zsrc;
        const half_t* x1p = (g2 == 0) ? &Xi[(w * 32 + 16 + c16) * 8] : zsrc;
        half8v bxi0 = *(const half8v*)x0p;
        half8v bxi1 = *(const half8v*)x1p;
        f32x4 U0 = {0.f, 0.f, 0.f, 0.f}, U1 = {0.f, 0.f, 0.f, 0.f};
        for (int j32 = 0; j32 < 16; ++j32) {
            half8v bKT = *(const half8v*)&KTb[c16 * 536 + j32 * 32 + g2 * 8];
            #pragma unroll
            for (int hh = 0; hh < 2; ++hh) {
                int jt16 = j32 * 2 + hh;
                const half_t* akp = (g2 == 0) ? &Kb[(jt16 * 16 + c16) * 8] : zsrc;
                half8v ak = *(const half8v*)akp;
                f32x4 S = {0.f, 0.f, 0.f, 0.f};
                S = __builtin_amdgcn_mfma_f32_16x16x32_f16(ak, bxi0, S, 0, 0, 0);
                half2v lo = pk2(__builtin_amdgcn_exp2f(S[0]), __builtin_amdgcn_exp2f(S[1]));
                half2v hi = pk2(__builtin_amdgcn_exp2f(S[2]), __builtin_amdgcn_exp2f(S[3]));
                half4v p = __builtin_shufflevector(lo, hi, 0, 1, 2, 3);
                *(half4v*)&myP[c16 * PB_STRIDE + hh * 16 + g2 * 4] = p;
            }
            {
                half4v alo = *(const half4v*)&myP[c16 * PB_STRIDE + g2 * 8];
                half4v ahi = *(const half4v*)&myP[c16 * PB_STRIDE + g2 * 8 + 4];
                half8v ap = __builtin_shufflevector(alo, ahi, 0, 1, 2, 3, 4, 5, 6, 7);
                U0 = __builtin_amdgcn_mfma_f32_16x16x32_f16(ap, bKT, U0, 0, 0, 0);
            }
            #pragma unroll
            for (int hh = 0; hh < 2; ++hh) {
                int jt16 = j32 * 2 + hh;
                const half_t* akp = (g2 == 0) ? &Kb[(jt16 * 16 + c16) * 8] : zsrc;
                half8v ak = *(const half8v*)akp;
                f32x4 S = {0.f, 0.f, 0.f, 0.f};
                S = __builtin_amdgcn_mfma_f32_16x16x32_f16(ak, bxi1, S, 0, 0, 0);
                half2v lo = pk2(__builtin_amdgcn_exp2f(S[0]), __builtin_amdgcn_exp2f(S[1]));
                half2v hi = pk2(__builtin_amdgcn_exp2f(S[2]), __builtin_amdgcn_exp2f(S[3]));
                half4v p = __builtin_shufflevector(lo, hi, 0, 1, 2, 3);
                *(half4v*)&myP[c16 * PB_STRIDE + hh * 16 + g2 * 4] = p;
            }
            {
                half4v alo = *(const half4v*)&myP[c16 * PB_STRIDE + g2 * 8];
                half4v ahi = *(const half4v*)&myP[c16 * PB_STRIDE + g2 * 8 + 4];
                half8v ap = __builtin_shufflevector(alo, ahi, 0, 1, 2, 3, 4, 5, 6, 7);
                U1 = __builtin_amdgcn_mfma_f32_16x16x32_f16(ap, bKT, U1, 0, 0, 0);
            }
        }
        int srcl = (lane & 48) | 8;
        #pragma unroll
        for (int r = 0; r < 4; ++r) {
            float l0 = __shfl(U0[r], srcl, 64);
            float l1 = __shfl(U1[r], srcl, 64);
            float inv0 = __builtin_amdgcn_rcpf(l0);
            float inv1 = __builtin_amdgcn_rcpf(l1);
            if (c16 < 8) {
                int i0 = w * 32 + g2 * 4 + r;
                int i1 = i0 + 16;
                if (it < 3) {
                    Xi[i0 * 8 + c16] = (half_t)(U0[r] * (C * inv0));
                    Xi[i1 * 8 + c16] = (half_t)(U1[r] * (C * inv1));
                } else {
                    fsum += (U0[r] * inv0) * wl2p[i0 * 8 + c16]
                          + (U1[r] * inv1) * wl2p[i1 * 8 + c16];
                }
            }
        }
    }
    float tot = block_reduce_256(fsum);
    if (t == 0) atomicAdd(&y[bh >> 3], tot);
    if (blockIdx.x == 0 && t < 32) {
        atomicAdd(&y[t], c0acc[0]);
    }
}

// ---------------------------------------------------------------------------
extern "C" void kernel_launch(void* const* d_in, const int* in_sizes, int n_in,
                              void* d_out, int out_size, void* d_ws, size_t ws_size,
                              hipStream_t stream) {
    const float* x   = (const float*)d_in[0];
    const float* g_q = (const float*)d_in[1];
    const float* b_q = (const float*)d_in[2];
    const float* g_k = (const float*)d_in[3];
    const float* b_k = (const float*)d_in[4];
    const float* g_v = (const float*)d_in[5];
    const float* b_v = (const float*)d_in[6];
    const float* Wq  = (const float*)d_in[7];
    const float* bq  = (const float*)d_in[8];
    const float* Wk  = (const float*)d_in[9];
    const float* bk  = (const float*)d_in[10];
    const float* Wv  = (const float*)d_in[11];
    const float* bv  = (const float*)d_in[12];
    const float* Wo  = (const float*)d_in[13];
    const float* bo  = (const float*)d_in[14];
    const float* Wl  = (const float*)d_in[15];
    const float* bl  = (const float*)d_in[16];
    float* out = (float*)d_out;

    float* ws = (float*)d_ws;
    float*  colsum = ws;                      // 192
    float*  b2     = ws + 192;                // 192
    float*  c0acc  = ws + 384;                // 1 (+pad to 64)
    float*  Wl2    = ws + 448;                // 32768
    half_t* WthF   = (half_t*)(ws + 33216);   // 98304 halves = 49152 floats
    half_t* qkv16  = (half_t*)(ws + 82368);   // 3*1048576 halves

    half_t* q16 = qkv16;
    half_t* k16 = qkv16 + 1048576;
    half_t* v16 = qkv16 + 2097152;

    prep_w    <<<192, 256, 0, stream>>>(Wq, Wk, Wv, g_q, g_k, g_v,
                                        b_q, b_k, b_v, bq, bk, bv, bl,
                                        WthF, colsum, b2, out, c0acc);
    ln_qkv_wl2<<<1056, 256, 0, stream>>>(x, WthF, b2, colsum, qkv16,
                                         Wl, Wo, bo, Wl2, c0acc);
    hopfield  <<<1024, 256, 0, stream>>>(q16, k16, v16, Wl2, c0acc, out);
}